// Round 6
// baseline (1006.955 us; speedup 1.0000x reference)
//
#include <hip/hip_runtime.h>

// OpeningP4: x [4,4,64,64,8] f32, kernel [3,3,3,8,16] f32 -> out [4,4,64,64,16] f32.
// v5: LDS-issue-bound fix. Erosion is column-per-thread (one (c,q) per thread, full
// 10-wide es row): ke loaded ONCE per phase into regs from GLOBAL (L1-resident, VMEM
// pipe) instead of 216 ds_read_b128 per phase; xs rows read as b128; dilation kd also
// from global/L1. Rotation algebra verbatim from the PASSED rounds (absmax 0.0625).

#define HH 64
#define WW 64
#define NEG_INF (-__builtin_inff())
#define POS_INF (__builtin_inff())

__device__ __forceinline__ float4 min4s(float4 a, float v, float4 k) {
    a.x = fminf(a.x, v - k.x); a.y = fminf(a.y, v - k.y);
    a.z = fminf(a.z, v - k.z); a.w = fminf(a.w, v - k.w);
    return a;
}

__global__ __launch_bounds__(256, 3) void opening_fused(
    const float* __restrict__ x,    // [4,4,64,64,8]
    const float* __restrict__ ker,  // [3,3,3,8,16]
    float* __restrict__ out)        // [4,4,64,64,16]
{
    // 18432 + 25856 = 44288 B -> 3 blocks/CU
    __shared__ __align__(16) float xs[8 * 4 * 144];  // [c][g][r*12+s], +inf padded
    __shared__ float4 es4[16 * 101];                 // col*101 + ey*10+ex, col=c4*4+q

    const int tid = threadIdx.x;
    const int tileX = blockIdx.x & 7;
    const int tileY = (blockIdx.x >> 3) & 7;
    const int j = (blockIdx.x >> 6) & 3;
    const int b = blockIdx.x >> 8;

    const float4* kg4 = (const float4*)ker;
    const float4* x4 = (const float4*)x;

    // ---- stage x tile: 4 planes, 12x12 halo, 8 c; OOB = +inf ----
    for (int t = tid; t < 1152; t += 256) {
        int q01 = t & 1;
        int cell = t >> 1;
        int g = cell / 144;
        int rem = cell - g * 144;
        int r = rem / 12;
        int s = rem - r * 12;
        int h = tileY * 8 - 2 + r;
        int w = tileX * 8 - 2 + s;
        float4 v;
        if ((unsigned)h < HH && (unsigned)w < WW)
            v = x4[(((b * 4 + g) * HH + h) * WW + w) * 2 + q01];
        else
            v = make_float4(POS_INF, POS_INF, POS_INF, POS_INF);
        int c0 = q01 * 4;
        xs[((c0 + 0) * 4 + g) * 144 + rem] = v.x;
        xs[((c0 + 1) * 4 + g) * 144 + rem] = v.y;
        xs[((c0 + 2) * 4 + g) * 144 + rem] = v.z;
        xs[((c0 + 3) * 4 + g) * 144 + rem] = v.w;
    }
    __syncthreads();

    // dilation ownership: one output pixel + f4 block per thread
    const int q_o = tid & 3;
    const int ox = (tid >> 2) & 7;
    const int oy = tid >> 5;

    // erosion ownership: threads 0..159 own (col = c4*4+q, row ey)
    const int ecol = (tid * 205) >> 11;   // tid/10, exact for tid<1024
    const int eey = tid - ecol * 10;
    const bool eact = tid < 160;

    float4 acc[8];
#pragma unroll
    for (int c = 0; c < 8; ++c)
        acc[c] = make_float4(NEG_INF, NEG_INF, NEG_INF, NEG_INF);

    for (int k = 0; k < 3; ++k) {
        const int gsrc = (j + k + 3) & 3;   // ero plane consumed at SE depth k
#pragma unroll
        for (int cg = 0; cg < 2; ++cg) {
            // ================= erosion (threads 0..159) =================
            if (eact) {
                const int cq = cg * 16 + ecol;          // (c*4+q) float4 offset
                const int c = cg * 4 + (ecol >> 2);
                const int hbase = tileY * 8 - 1 + eey;
                const bool rowok = (unsigned)hbase < HH;
#pragma unroll
                for (int half = 0; half < 2; ++half) {
                    float4 p0, p1, p2, p3, p4;
                    p0 = p1 = p2 = p3 = p4 = make_float4(POS_INF, POS_INF, POS_INF, POS_INF);
#pragma unroll
                    for (int k2 = 0; k2 < 3; ++k2) {
                        const int g2 = (gsrc + k2 + 3) & 3;
                        // ---- ke[9] from global (L1-resident); indices block-uniform ----
                        float4 ke[9];
#pragma unroll
                        for (int dy = 0; dy < 3; ++dy)
#pragma unroll
                            for (int dx = 0; dx < 3; ++dx) {
                                int a0 = 2 - dy, b0 = 2 - dx;
                                int i, jj;
                                switch (gsrc) {
                                    case 0:  i = a0;      jj = b0;      break;
                                    case 1:  i = b0;      jj = 2 - a0;  break;
                                    case 2:  i = 2 - a0;  jj = 2 - b0;  break;
                                    default: i = 2 - b0;  jj = a0;      break;
                                }
                                int ka, kb, kc;
                                if (k2 == 0)      { ka = 2 - jj; kb = i;      kc = 2; }
                                else if (k2 == 1) { ka = i;      kb = jj;     kc = 1; }
                                else              { ka = jj;     kb = 2 - i;  kc = 0; }
                                ke[dy * 3 + dx] = kg4[((ka * 3 + kb) * 3 + kc) * 32 + cq];
                            }
#pragma unroll
                        for (int dy = 0; dy < 3; ++dy) {
                            const float4* xr4 =
                                (const float4*)&xs[(c * 4 + g2) * 144 + (eey + dy) * 12];
                            float4 xa = xr4[half];
                            float4 xb = xr4[half + 1];
                            float xr[8] = {xa.x, xa.y, xa.z, xa.w, xb.x, xb.y, xb.z, xb.w};
#pragma unroll
                            for (int dx = 0; dx < 3; ++dx) {
                                float4 kv = ke[dy * 3 + dx];
                                p0 = min4s(p0, xr[half + 0 + dx], kv);
                                p1 = min4s(p1, xr[half + 1 + dx], kv);
                                p2 = min4s(p2, xr[half + 2 + dx], kv);
                                p3 = min4s(p3, xr[half + 3 + dx], kv);
                                p4 = min4s(p4, xr[half + 4 + dx], kv);
                            }
                        }
                    }
                    // validity (+inf pad can leak finite values at image edges) + store
                    const int wbase = tileX * 8 - 1 + half * 5;
                    const int ebase = ecol * 101 + eey * 10 + half * 5;
                    const float4 ninf = make_float4(NEG_INF, NEG_INF, NEG_INF, NEG_INF);
                    es4[ebase + 0] = (rowok && (unsigned)(wbase + 0) < WW) ? p0 : ninf;
                    es4[ebase + 1] = (rowok && (unsigned)(wbase + 1) < WW) ? p1 : ninf;
                    es4[ebase + 2] = (rowok && (unsigned)(wbase + 2) < WW) ? p2 : ninf;
                    es4[ebase + 3] = (rowok && (unsigned)(wbase + 3) < WW) ? p3 : ninf;
                    es4[ebase + 4] = (rowok && (unsigned)(wbase + 4) < WW) ? p4 : ninf;
                }
            }
            __syncthreads();

            // ================= dilation accumulate (all 256 threads) =================
#pragma unroll
            for (int c4 = 0; c4 < 4; ++c4) {
                float4 a = acc[cg * 4 + c4];
#pragma unroll
                for (int dy = 0; dy < 3; ++dy)
#pragma unroll
                    for (int dx = 0; dx < 3; ++dx) {
                        int i, jj;
                        switch (j) {
                            case 0:  i = dy;      jj = dx;      break;
                            case 1:  i = dx;      jj = 2 - dy;  break;
                            case 2:  i = 2 - dy;  jj = 2 - dx;  break;
                            default: i = 2 - dx;  jj = dy;      break;
                        }
                        float4 kv = kg4[((i * 3 + jj) * 3 + k) * 32 + cg * 16 + c4 * 4 + q_o];
                        float4 e = es4[(c4 * 4 + q_o) * 101 + (oy + dy) * 10 + (ox + dx)];
                        a.x = fmaxf(a.x, e.x + kv.x);
                        a.y = fmaxf(a.y, e.y + kv.y);
                        a.z = fmaxf(a.z, e.z + kv.z);
                        a.w = fmaxf(a.w, e.w + kv.w);
                    }
                acc[cg * 4 + c4] = a;
            }
            __syncthreads();   // before next phase overwrites es4
        }
    }

    // ---- epilogue: sum over c, coalesced float4 store ----
    float4 s = acc[0];
#pragma unroll
    for (int c = 1; c < 8; ++c) {
        s.x += acc[c].x; s.y += acc[c].y; s.z += acc[c].z; s.w += acc[c].w;
    }
    const int h = tileY * 8 + oy;
    const int w = tileX * 8 + ox;
    float4* out4 = (float4*)out;
    out4[(((b * 4 + j) * HH + h) * WW + w) * 4 + q_o] = s;
}

extern "C" void kernel_launch(void* const* d_in, const int* in_sizes, int n_in,
                              void* d_out, int out_size, void* d_ws, size_t ws_size,
                              hipStream_t stream) {
    const float* x = (const float*)d_in[0];
    const float* ker = (const float*)d_in[1];
    float* out = (float*)d_out;
    (void)d_ws; (void)ws_size;

    opening_fused<<<1024, 256, 0, stream>>>(x, ker, out);
}

// Round 7
// 406.036 us; speedup vs baseline: 2.4800x; 2.4800x over previous
//
#include <hip/hip_runtime.h>

// OpeningP4: x [4,4,64,64,8] f32, kernel [3,3,3,8,16] f32 -> out [4,4,64,64,16] f32.
// v6 = R5 (258us, PASSED) + column-per-thread erosion with ke hoisted from LDS into
// registers (27 b128 instead of 216 per thread/phase). R6's global-ke experiment
// regressed 4x (890MB HBM fetch) -> reverted to LDS-resident kernel tables.
// Staging + dilation index math verbatim from PASSED rounds (absmax 0.0625).

#define HH 64
#define WW 64
#define NEG_INF (-__builtin_inff())
#define POS_INF (__builtin_inff())

__global__ __launch_bounds__(256, 3) void opening_fused(
    const float* __restrict__ x,    // [4,4,64,64,8]
    const float* __restrict__ ker,  // [3,3,3,8,16]
    float* __restrict__ out)        // [4,4,64,64,16]
{
    // 18432 + 25856 + 6912 + 2304 = 53504 B -> 3 blocks/CU (160512 <= 163840)
    __shared__ __align__(16) float xs[8 * 4 * 144];  // [c][g][r*12+s], +inf padded
    __shared__ float4 es4[16 * 101];                 // [col(=c4*4+q)][ey*10+ex]
    __shared__ float4 ke4[27 * 16];                  // [tap=(dy*3+dx)*3+k2][c4*4+q]
    __shared__ float4 kd4[9 * 16];                   // [dy*3+dx][c4*4+q]

    const int tid = threadIdx.x;
    const int tileX = blockIdx.x & 7;
    const int tileY = (blockIdx.x >> 3) & 7;
    const int j = (blockIdx.x >> 6) & 3;
    const int b = blockIdx.x >> 8;

    const float4* ker4 = (const float4*)ker;
    const float4* x4 = (const float4*)x;

    // ---- stage x tile: 4 planes, 12x12 halo, 8 c; OOB = +inf ----
    for (int t = tid; t < 1152; t += 256) {
        int q01 = t & 1;
        int cell = t >> 1;
        int g = cell / 144;
        int rem = cell - g * 144;
        int r = rem / 12;
        int s = rem - r * 12;
        int h = tileY * 8 - 2 + r;
        int w = tileX * 8 - 2 + s;
        float4 v;
        if ((unsigned)h < HH && (unsigned)w < WW)
            v = x4[(((b * 4 + g) * HH + h) * WW + w) * 2 + q01];
        else
            v = make_float4(POS_INF, POS_INF, POS_INF, POS_INF);
        int c0 = q01 * 4;
        xs[((c0 + 0) * 4 + g) * 144 + rem] = v.x;
        xs[((c0 + 1) * 4 + g) * 144 + rem] = v.y;
        xs[((c0 + 2) * 4 + g) * 144 + rem] = v.z;
        xs[((c0 + 3) * 4 + g) * 144 + rem] = v.w;
    }
    __syncthreads();

    // dilation ownership
    const int q_o = tid & 3;
    const int ox = (tid >> 2) & 7;
    const int oy = tid >> 5;

    // erosion ownership: threads 0..159 own (ecol = c4*4+q, row eey)
    const int ecol = (tid * 205) >> 11;   // tid/10 for tid<1024
    const int eey = tid - ecol * 10;
    const bool eact = tid < 160;

    float4 acc[8];
#pragma unroll
    for (int c = 0; c < 8; ++c)
        acc[c] = make_float4(NEG_INF, NEG_INF, NEG_INF, NEG_INF);

    for (int k = 0; k < 3; ++k) {
        const int gsrc = (j + k + 3) & 3;   // ero plane consumed at SE depth k
#pragma unroll
        for (int cg = 0; cg < 2; ++cg) {
            // ---- stage KE (432 f4) + kd (144 f4) — verbatim from PASSED R5 ----
            for (int t = tid; t < 576; t += 256) {
                if (t < 432) {
                    int q = t & 3;
                    int c4 = (t >> 2) & 3;
                    int tap = t >> 4;
                    int k2 = tap % 3;
                    int dxdy = tap / 3;
                    int dx = dxdy % 3;
                    int dy = dxdy / 3;
                    int a0 = 2 - dy, b0 = 2 - dx;
                    int i, jj;
                    switch (gsrc) {
                        case 0:  i = a0;      jj = b0;      break;
                        case 1:  i = b0;      jj = 2 - a0;  break;
                        case 2:  i = 2 - a0;  jj = 2 - b0;  break;
                        default: i = 2 - b0;  jj = a0;      break;
                    }
                    int ka, kb, kc;
                    if (k2 == 0)      { ka = 2 - jj; kb = i;      kc = 2; }
                    else if (k2 == 1) { ka = i;      kb = jj;     kc = 1; }
                    else              { ka = jj;     kb = 2 - i;  kc = 0; }
                    int c = cg * 4 + c4;
                    ke4[t] = ker4[((ka * 3 + kb) * 3 + kc) * 32 + c * 4 + q];
                } else {
                    int u = t - 432;
                    int q = u & 3;
                    int c4 = (u >> 2) & 3;
                    int dydx = u >> 4;
                    int dx = dydx % 3;
                    int dy = dydx / 3;
                    int i, jj;
                    switch (j) {
                        case 0:  i = dy;      jj = dx;      break;
                        case 1:  i = dx;      jj = 2 - dy;  break;
                        case 2:  i = 2 - dy;  jj = 2 - dx;  break;
                        default: i = 2 - dx;  jj = dy;      break;
                    }
                    int c = cg * 4 + c4;
                    kd4[u] = ker4[((i * 3 + jj) * 3 + k) * 32 + c * 4 + q];
                }
            }
            __syncthreads();

            // ---- erosion: thread owns (ecol, eey); ke hoisted to regs per k2 ----
            if (eact) {
                const int c = cg * 4 + (ecol >> 2);
                const int hbase = tileY * 8 - 1 + eey;
                const bool rowok = (unsigned)hbase < HH;
                float4 p0, p1, p2, p3, p4, p5, p6, p7, p8, p9;
                p0 = p1 = p2 = p3 = p4 = p5 = p6 = p7 = p8 = p9 =
                    make_float4(POS_INF, POS_INF, POS_INF, POS_INF);
#pragma unroll
                for (int k2 = 0; k2 < 3; ++k2) {
                    const int g2 = (gsrc + k2 + 3) & 3;
                    float4 ke9[9];
#pragma unroll
                    for (int t9 = 0; t9 < 9; ++t9)
                        ke9[t9] = ke4[(t9 * 3 + k2) * 16 + ecol];
#pragma unroll
                    for (int dy = 0; dy < 3; ++dy) {
                        const float4* xr4 =
                            (const float4*)&xs[(c * 4 + g2) * 144 + (eey + dy) * 12];
                        float4 xa = xr4[0], xb = xr4[1], xc = xr4[2];
                        float xw[12] = {xa.x, xa.y, xa.z, xa.w,
                                        xb.x, xb.y, xb.z, xb.w,
                                        xc.x, xc.y, xc.z, xc.w};
#pragma unroll
                        for (int dx = 0; dx < 3; ++dx) {
                            float4 kv = ke9[dy * 3 + dx];
#define UPD(P, V) P.x = fminf(P.x, (V) - kv.x); P.y = fminf(P.y, (V) - kv.y); \
                  P.z = fminf(P.z, (V) - kv.z); P.w = fminf(P.w, (V) - kv.w)
                            UPD(p0, xw[0 + dx]); UPD(p1, xw[1 + dx]);
                            UPD(p2, xw[2 + dx]); UPD(p3, xw[3 + dx]);
                            UPD(p4, xw[4 + dx]); UPD(p5, xw[5 + dx]);
                            UPD(p6, xw[6 + dx]); UPD(p7, xw[7 + dx]);
                            UPD(p8, xw[8 + dx]); UPD(p9, xw[9 + dx]);
#undef UPD
                        }
                    }
                }
                // validity + store (pixel OOB -> -inf so dilation needs no checks)
                const int wb = tileX * 8 - 1;
                const int ebase = ecol * 101 + eey * 10;
                const float4 ninf = make_float4(NEG_INF, NEG_INF, NEG_INF, NEG_INF);
                es4[ebase + 0] = (rowok && (unsigned)(wb + 0) < WW) ? p0 : ninf;
                es4[ebase + 1] = (rowok && (unsigned)(wb + 1) < WW) ? p1 : ninf;
                es4[ebase + 2] = (rowok && (unsigned)(wb + 2) < WW) ? p2 : ninf;
                es4[ebase + 3] = (rowok && (unsigned)(wb + 3) < WW) ? p3 : ninf;
                es4[ebase + 4] = (rowok && (unsigned)(wb + 4) < WW) ? p4 : ninf;
                es4[ebase + 5] = (rowok && (unsigned)(wb + 5) < WW) ? p5 : ninf;
                es4[ebase + 6] = (rowok && (unsigned)(wb + 6) < WW) ? p6 : ninf;
                es4[ebase + 7] = (rowok && (unsigned)(wb + 7) < WW) ? p7 : ninf;
                es4[ebase + 8] = (rowok && (unsigned)(wb + 8) < WW) ? p8 : ninf;
                es4[ebase + 9] = (rowok && (unsigned)(wb + 9) < WW) ? p9 : ninf;
            }
            __syncthreads();

            // ---- dilation accumulate (all 256 threads) — R5 pattern, stride 101 ----
#pragma unroll
            for (int c4 = 0; c4 < 4; ++c4) {
                float4 a = acc[cg * 4 + c4];
#pragma unroll
                for (int dy = 0; dy < 3; ++dy)
#pragma unroll
                    for (int dx = 0; dx < 3; ++dx) {
                        int pos = (oy + dy) * 10 + (ox + dx);
                        float4 e = es4[(c4 * 4 + q_o) * 101 + pos];
                        float4 kv = kd4[(dy * 3 + dx) * 16 + c4 * 4 + q_o];
                        a.x = fmaxf(a.x, e.x + kv.x);
                        a.y = fmaxf(a.y, e.y + kv.y);
                        a.z = fmaxf(a.z, e.z + kv.z);
                        a.w = fmaxf(a.w, e.w + kv.w);
                    }
                acc[cg * 4 + c4] = a;
            }
            __syncthreads();   // before next phase overwrites ke4/kd4/es4
        }
    }

    // ---- epilogue: sum over c, coalesced float4 store ----
    float4 s = acc[0];
#pragma unroll
    for (int c = 1; c < 8; ++c) {
        s.x += acc[c].x; s.y += acc[c].y; s.z += acc[c].z; s.w += acc[c].w;
    }
    const int h = tileY * 8 + oy;
    const int w = tileX * 8 + ox;
    float4* out4 = (float4*)out;
    out4[(((b * 4 + j) * HH + h) * WW + w) * 4 + q_o] = s;
}

extern "C" void kernel_launch(void* const* d_in, const int* in_sizes, int n_in,
                              void* d_out, int out_size, void* d_ws, size_t ws_size,
                              hipStream_t stream) {
    const float* x = (const float*)d_in[0];
    const float* ker = (const float*)d_in[1];
    float* out = (float*)d_out;
    (void)d_ws; (void)ws_size;

    opening_fused<<<1024, 256, 0, stream>>>(x, ker, out);
}

// Round 8
// 141.391 us; speedup vs baseline: 7.1218x; 2.8717x over previous
//
#include <hip/hip_runtime.h>

// OpeningP4: x [4,4,64,64,8] f32, kernel [3,3,3,8,16] f32 -> out [4,4,64,64,16] f32.
// v8: two-kernel design through d_ws (erosion computed ONCE, not 3x as in the fused
// versions). Thread owns (c, f4): kernel taps in REGISTERS (wave-coalesced 512B global
// reads), erosion x-taps from conflict-free LDS tile, dilation LDS-free with coalesced
// 512B/px ero reads + xor-shuffle c-reduction. Guarded on ws_size with the PASSED
// 258us fused kernel as fallback (container-death insurance).
// Rotation algebra verbatim from the PASSED rounds (absmax 0.0625).

#define HH 64
#define WW 64
#define NEG_INF (-__builtin_inff())
#define POS_INF (__builtin_inff())

#define ROT_G(G, A, B, I, J) do { switch (G) { \
    case 0:  I = (A);     J = (B);     break; \
    case 1:  I = (B);     J = 2 - (A); break; \
    case 2:  I = 2 - (A); J = 2 - (B); break; \
    default: I = 2 - (B); J = (A);     break; } } while (0)

// ======================= kernel 1: erosion ==========================
// ero[b,g,h,w,c,f] = min_{k2,dy,dx} x[(g+k2-1)&3, h+dy-1, w+dx-1, c] - KE_g[dy,dx,k2,c,f]
// block = (b,g,h-row); thread = (slot, c, q); pixels w = slot + 8i.
__global__ __launch_bounds__(256) void erode_k(const float* __restrict__ x,
                                               const float* __restrict__ ker,
                                               float* __restrict__ ero) {
    __shared__ float4 xs4[1188];   // [p][r][wp][q01]: ((p*3+r)*66+wp)*2+q01 ; 19008 B

    const int tid = threadIdx.x;
    const int h = blockIdx.x & 63;
    const int g = (blockIdx.x >> 6) & 3;
    const int b = blockIdx.x >> 8;

    const float4* x4 = (const float4*)x;
    const float4* ker4 = (const float4*)ker;

    // stage 3 source planes x[(g+p-1)&3], rows h-1..h+1, cols -1..64, all 8 c; OOB=+inf
    for (int t = tid; t < 1188; t += 256) {
        int q01 = t & 1;
        int u = t >> 1;          // [0,594)
        int wp = u % 66;
        int v = u / 66;          // [0,9)
        int r = v % 3;
        int p = v / 3;
        int g2 = (g + p + 3) & 3;
        int h2 = h - 1 + r;
        int w2 = wp - 1;
        float4 vv;
        if ((unsigned)h2 < HH && (unsigned)w2 < WW)
            vv = x4[(((b * 4 + g2) * HH + h2) * WW + w2) * 2 + q01];
        else
            vv = make_float4(POS_INF, POS_INF, POS_INF, POS_INF);
        xs4[((p * 3 + r) * 66 + wp) * 2 + q01] = vv;
    }
    __syncthreads();

    const int q = tid & 3;
    const int c = (tid >> 2) & 7;
    const int slot = tid >> 5;
    const float* xsf = (const float*)xs4;

    float4 acc[8];
#pragma unroll
    for (int i = 0; i < 8; ++i)
        acc[i] = make_float4(POS_INF, POS_INF, POS_INF, POS_INF);

#pragma unroll
    for (int k2 = 0; k2 < 3; ++k2) {
        // KE_g[dy,dx,k2,c,f4=q] in registers: 9 coalesced 512B wave reads (L1-hot)
        float4 ke9[9];
#pragma unroll
        for (int t9 = 0; t9 < 9; ++t9) {
            int dy = t9 / 3, dx = t9 % 3;
            int a0 = 2 - dy, b0 = 2 - dx;
            int i, jj;
            ROT_G(g, a0, b0, i, jj);
            int ka, kb, kc;
            if (k2 == 0)      { ka = 2 - jj; kb = i;      kc = 2; }
            else if (k2 == 1) { ka = i;      kb = jj;     kc = 1; }
            else              { ka = jj;     kb = 2 - i;  kc = 0; }
            ke9[t9] = ker4[((ka * 3 + kb) * 3 + kc) * 32 + c * 4 + q];
        }
#pragma unroll
        for (int dy = 0; dy < 3; ++dy)
#pragma unroll
            for (int dx = 0; dx < 3; ++dx) {
                float4 kv = ke9[dy * 3 + dx];
                int base = ((k2 * 3 + dy) * 66 + slot + dx) * 8 + c;
#pragma unroll
                for (int i = 0; i < 8; ++i) {
                    float v = xsf[base + i * 64];   // conflict-free: banks slot*8+c
                    acc[i].x = fminf(acc[i].x, v - kv.x);
                    acc[i].y = fminf(acc[i].y, v - kv.y);
                    acc[i].z = fminf(acc[i].z, v - kv.z);
                    acc[i].w = fminf(acc[i].w, v - kv.w);
                }
            }
    }

    // store: ero f4 idx = (((b*4+g)*64+h)*64 + w)*32 + c*4 + q, w = slot + 8i
    float4* ero4 = (float4*)ero;
    const size_t obase = (((size_t)(b * 4 + g) * HH + h) * WW + slot) * 32 + c * 4 + q;
#pragma unroll
    for (int i = 0; i < 8; ++i)
        ero4[obase + (size_t)i * 256] = acc[i];
}

// ======================= kernel 2: dilation =========================
// out[b,j,h,w,f] = sum_c max_{k,dy,dx} ero[(j+k-1)&3, h+dy-1, w+dx-1, c, f]
//                                      + kernel[r_j(dy,dx)][k][c][f]
// thread = (slot, c, q), px = blockIdx*8+slot; no LDS; c-sum via xor-shuffle.
__global__ __launch_bounds__(256) void dilate_k(const float* __restrict__ ero,
                                                const float* __restrict__ ker,
                                                float* __restrict__ out) {
    const int tid = threadIdx.x;
    const int q = tid & 3;
    const int c = (tid >> 2) & 7;
    const int slot = tid >> 5;
    const int px = blockIdx.x * 8 + slot;
    const int w = px & 63;
    const int h = (px >> 6) & 63;
    const int j = (px >> 12) & 3;   // uniform within block
    const int b = px >> 14;

    const float4* ker4 = (const float4*)ker;
    const float4* ero4 = (const float4*)ero;

    float4 acc = make_float4(NEG_INF, NEG_INF, NEG_INF, NEG_INF);

#pragma unroll
    for (int k = 0; k < 3; ++k) {
        const int gsrc = (j + k + 3) & 3;
        float4 kd9[9];
#pragma unroll
        for (int t9 = 0; t9 < 9; ++t9) {
            int dy = t9 / 3, dx = t9 % 3;
            int i, jj;
            ROT_G(j, dy, dx, i, jj);
            kd9[t9] = ker4[((i * 3 + jj) * 3 + k) * 32 + c * 4 + q];
        }
        const size_t pbase = ((size_t)(b * 4 + gsrc) * HH * WW) * 32 + c * 4 + q;
#pragma unroll
        for (int dy = 0; dy < 3; ++dy) {
            int hh = h + dy - 1;
            if ((unsigned)hh >= HH) continue;
#pragma unroll
            for (int dx = 0; dx < 3; ++dx) {
                int ww = w + dx - 1;
                if ((unsigned)ww >= WW) continue;
                float4 e = ero4[pbase + (size_t)(hh * WW + ww) * 32];
                float4 kv = kd9[dy * 3 + dx];
                acc.x = fmaxf(acc.x, e.x + kv.x);
                acc.y = fmaxf(acc.y, e.y + kv.y);
                acc.z = fmaxf(acc.z, e.z + kv.z);
                acc.w = fmaxf(acc.w, e.w + kv.w);
            }
        }
    }

    // sum over c: lanes differ in c at stride 4 within the 64-lane wave
#pragma unroll
    for (int off = 4; off <= 16; off <<= 1) {
        acc.x += __shfl_xor(acc.x, off, 64);
        acc.y += __shfl_xor(acc.y, off, 64);
        acc.z += __shfl_xor(acc.z, off, 64);
        acc.w += __shfl_xor(acc.w, off, 64);
    }
    if (c == 0)
        ((float4*)out)[(size_t)px * 4 + q] = acc;
}

// ============== fallback: PASSED fused kernel (258 us, R5) ==============
__global__ __launch_bounds__(256, 3) void opening_fused_fb(
    const float* __restrict__ x, const float* __restrict__ ker, float* __restrict__ out)
{
    __shared__ __align__(16) float xs[8 * 4 * 144];
    __shared__ float4 es4[4 * 4 * 100];
    __shared__ float4 ke4[27 * 4 * 4];
    __shared__ float4 kd4[9 * 4 * 4];

    const int tid = threadIdx.x;
    const int tileX = blockIdx.x & 7;
    const int tileY = (blockIdx.x >> 3) & 7;
    const int j = (blockIdx.x >> 6) & 3;
    const int b = blockIdx.x >> 8;
    const float4* ker4 = (const float4*)ker;
    const float4* x4 = (const float4*)x;

    for (int t = tid; t < 1152; t += 256) {
        int q01 = t & 1;
        int cell = t >> 1;
        int g = cell / 144;
        int rem = cell - g * 144;
        int r = rem / 12;
        int s = rem - r * 12;
        int h = tileY * 8 - 2 + r;
        int w = tileX * 8 - 2 + s;
        float4 v;
        if ((unsigned)h < HH && (unsigned)w < WW)
            v = x4[(((b * 4 + g) * HH + h) * WW + w) * 2 + q01];
        else
            v = make_float4(POS_INF, POS_INF, POS_INF, POS_INF);
        int c0 = q01 * 4;
        xs[((c0 + 0) * 4 + g) * 144 + rem] = v.x;
        xs[((c0 + 1) * 4 + g) * 144 + rem] = v.y;
        xs[((c0 + 2) * 4 + g) * 144 + rem] = v.z;
        xs[((c0 + 3) * 4 + g) * 144 + rem] = v.w;
    }
    __syncthreads();

    const int q_o = tid & 3;
    const int ox = (tid >> 2) & 7;
    const int oy = tid >> 5;

    float4 acc[8];
#pragma unroll
    for (int c = 0; c < 8; ++c)
        acc[c] = make_float4(NEG_INF, NEG_INF, NEG_INF, NEG_INF);

    for (int k = 0; k < 3; ++k) {
        const int gsrc = (j + k + 3) & 3;
#pragma unroll
        for (int cg = 0; cg < 2; ++cg) {
            for (int t = tid; t < 576; t += 256) {
                if (t < 432) {
                    int q = t & 3;
                    int c4 = (t >> 2) & 3;
                    int tap = t >> 4;
                    int k2 = tap % 3;
                    int dxdy = tap / 3;
                    int dx = dxdy % 3;
                    int dy = dxdy / 3;
                    int a0 = 2 - dy, b0 = 2 - dx;
                    int i, jj;
                    ROT_G(gsrc, a0, b0, i, jj);
                    int ka, kb, kc;
                    if (k2 == 0)      { ka = 2 - jj; kb = i;      kc = 2; }
                    else if (k2 == 1) { ka = i;      kb = jj;     kc = 1; }
                    else              { ka = jj;     kb = 2 - i;  kc = 0; }
                    int c = cg * 4 + c4;
                    ke4[t] = ker4[((ka * 3 + kb) * 3 + kc) * 32 + c * 4 + q];
                } else {
                    int u = t - 432;
                    int q = u & 3;
                    int c4 = (u >> 2) & 3;
                    int dydx = u >> 4;
                    int dx = dydx % 3;
                    int dy = dydx / 3;
                    int i, jj;
                    ROT_G(j, dy, dx, i, jj);
                    int c = cg * 4 + c4;
                    kd4[u] = ker4[((i * 3 + jj) * 3 + k) * 32 + c * 4 + q];
                }
            }
            __syncthreads();

            for (int it = 0; it < 2; ++it) {
                int id = tid + (it << 8);
                int c4 = id >> 7;
                int p = id & 127;
                if (p >= 100) continue;
                int ey = (p * 205) >> 11;
                int ex = p - ey * 10;
                int h_es = tileY * 8 - 1 + ey;
                int w_es = tileX * 8 - 1 + ex;
                float4 b0, b1, b2, b3;
                if ((unsigned)h_es < HH && (unsigned)w_es < WW) {
                    b0 = b1 = b2 = b3 = make_float4(POS_INF, POS_INF, POS_INF, POS_INF);
                    int c = cg * 4 + c4;
#pragma unroll
                    for (int k2 = 0; k2 < 3; ++k2) {
                        int g2 = (gsrc + k2 + 3) & 3;
                        int base = (c * 4 + g2) * 144 + ey * 12 + ex;
#pragma unroll
                        for (int dy = 0; dy < 3; ++dy)
#pragma unroll
                            for (int dx = 0; dx < 3; ++dx) {
                                float v = xs[base + dy * 12 + dx];
                                const float4* kk = &ke4[(((dy * 3 + dx) * 3 + k2) * 4 + c4) * 4];
                                float4 kv;
                                kv = kk[0];
                                b0.x = fminf(b0.x, v - kv.x); b0.y = fminf(b0.y, v - kv.y);
                                b0.z = fminf(b0.z, v - kv.z); b0.w = fminf(b0.w, v - kv.w);
                                kv = kk[1];
                                b1.x = fminf(b1.x, v - kv.x); b1.y = fminf(b1.y, v - kv.y);
                                b1.z = fminf(b1.z, v - kv.z); b1.w = fminf(b1.w, v - kv.w);
                                kv = kk[2];
                                b2.x = fminf(b2.x, v - kv.x); b2.y = fminf(b2.y, v - kv.y);
                                b2.z = fminf(b2.z, v - kv.z); b2.w = fminf(b2.w, v - kv.w);
                                kv = kk[3];
                                b3.x = fminf(b3.x, v - kv.x); b3.y = fminf(b3.y, v - kv.y);
                                b3.z = fminf(b3.z, v - kv.z); b3.w = fminf(b3.w, v - kv.w);
                            }
                    }
                } else {
                    b0 = b1 = b2 = b3 = make_float4(NEG_INF, NEG_INF, NEG_INF, NEG_INF);
                }
                int eb = (c4 * 4) * 100 + p;
                es4[eb] = b0; es4[eb + 100] = b1; es4[eb + 200] = b2; es4[eb + 300] = b3;
            }
            __syncthreads();

#pragma unroll
            for (int c4 = 0; c4 < 4; ++c4) {
                float4 a = acc[cg * 4 + c4];
#pragma unroll
                for (int dy = 0; dy < 3; ++dy)
#pragma unroll
                    for (int dx = 0; dx < 3; ++dx) {
                        int pos = (oy + dy) * 10 + (ox + dx);
                        float4 e = es4[(c4 * 4 + q_o) * 100 + pos];
                        float4 kv = kd4[(dy * 3 + dx) * 16 + c4 * 4 + q_o];
                        a.x = fmaxf(a.x, e.x + kv.x);
                        a.y = fmaxf(a.y, e.y + kv.y);
                        a.z = fmaxf(a.z, e.z + kv.z);
                        a.w = fmaxf(a.w, e.w + kv.w);
                    }
                acc[cg * 4 + c4] = a;
            }
            __syncthreads();
        }
    }

    float4 s = acc[0];
#pragma unroll
    for (int c = 1; c < 8; ++c) {
        s.x += acc[c].x; s.y += acc[c].y; s.z += acc[c].z; s.w += acc[c].w;
    }
    const int h = tileY * 8 + oy;
    const int w = tileX * 8 + ox;
    ((float4*)out)[(((b * 4 + j) * HH + h) * WW + w) * 4 + q_o] = s;
}

extern "C" void kernel_launch(void* const* d_in, const int* in_sizes, int n_in,
                              void* d_out, int out_size, void* d_ws, size_t ws_size,
                              hipStream_t stream) {
    const float* x = (const float*)d_in[0];
    const float* ker = (const float*)d_in[1];
    float* out = (float*)d_out;

    const size_t ero_bytes = (size_t)4 * 4 * HH * WW * 8 * 16 * sizeof(float); // 33.5 MB

    if (ws_size >= ero_bytes) {
        float* ero = (float*)d_ws;
        erode_k<<<1024, 256, 0, stream>>>(x, ker, ero);     // (b,g,row)
        dilate_k<<<8192, 256, 0, stream>>>(ero, ker, out);  // 65536 px * 32 (c,q) / 256
    } else {
        opening_fused_fb<<<1024, 256, 0, stream>>>(x, ker, out);
    }
}

// Round 9
// 133.803 us; speedup vs baseline: 7.5256x; 1.0567x over previous
//
#include <hip/hip_runtime.h>

// OpeningP4: x [4,4,64,64,8] f32, kernel [3,3,3,8,16] f32 -> out [4,4,64,64,16] f32.
// v9 = R8 (141us PASSED) + dilate instruction-diet:
//  - ero stored PADDED in w (wp=0..65, -inf borders) -> no column bounds checks,
//    taps = 3 loads at immediate offsets off one base
//  - dilate block=(b,j,h): row checks wave-uniform; 8 px/thread amortizes kd9 regs
//  - ws ladder: padded (34.6MB) -> unpadded same structure (32MiB, R8-proven) -> fused.
// Erosion compute + rotation algebra verbatim from PASSED rounds (absmax 0.0625).

#define HH 64
#define WW 64
#define NEG_INF (-__builtin_inff())
#define POS_INF (__builtin_inff())

#define ROT_G(G, A, B, I, J) do { switch (G) { \
    case 0:  I = (A);     J = (B);     break; \
    case 1:  I = (B);     J = 2 - (A); break; \
    case 2:  I = 2 - (A); J = 2 - (B); break; \
    default: I = 2 - (B); J = (A);     break; } } while (0)

// ======================= kernel 1: erosion ==========================
// block = (b,g,h); thread = (slot,c,q); pixels w = slot + 8i.
// PADW=66: store at wp=w+1, write -inf borders wp=0,65.  PADW=64: R8 layout.
template <int PADW>
__global__ __launch_bounds__(256) void erode_t(const float* __restrict__ x,
                                               const float* __restrict__ ker,
                                               float* __restrict__ ero) {
    __shared__ float4 xs4[1188];   // [p][r][wp0..65][q01] ; 19008 B

    const int tid = threadIdx.x;
    const int h = blockIdx.x & 63;
    const int g = (blockIdx.x >> 6) & 3;
    const int b = blockIdx.x >> 8;

    const float4* x4 = (const float4*)x;
    const float4* ker4 = (const float4*)ker;

    // stage 3 source planes x[(g+p-1)&3], rows h-1..h+1, cols -1..64, all 8 c; OOB=+inf
    for (int t = tid; t < 1188; t += 256) {
        int q01 = t & 1;
        int u = t >> 1;
        int wp = u % 66;
        int v = u / 66;
        int r = v % 3;
        int p = v / 3;
        int g2 = (g + p + 3) & 3;
        int h2 = h - 1 + r;
        int w2 = wp - 1;
        float4 vv;
        if ((unsigned)h2 < HH && (unsigned)w2 < WW)
            vv = x4[(((b * 4 + g2) * HH + h2) * WW + w2) * 2 + q01];
        else
            vv = make_float4(POS_INF, POS_INF, POS_INF, POS_INF);
        xs4[((p * 3 + r) * 66 + wp) * 2 + q01] = vv;
    }
    __syncthreads();

    const int q = tid & 3;
    const int c = (tid >> 2) & 7;
    const int slot = tid >> 5;
    const float* xsf = (const float*)xs4;

    float4 acc[8];
#pragma unroll
    for (int i = 0; i < 8; ++i)
        acc[i] = make_float4(POS_INF, POS_INF, POS_INF, POS_INF);

#pragma unroll
    for (int k2 = 0; k2 < 3; ++k2) {
        float4 ke9[9];
#pragma unroll
        for (int t9 = 0; t9 < 9; ++t9) {
            int dy = t9 / 3, dx = t9 % 3;
            int a0 = 2 - dy, b0 = 2 - dx;
            int i, jj;
            ROT_G(g, a0, b0, i, jj);
            int ka, kb, kc;
            if (k2 == 0)      { ka = 2 - jj; kb = i;      kc = 2; }
            else if (k2 == 1) { ka = i;      kb = jj;     kc = 1; }
            else              { ka = jj;     kb = 2 - i;  kc = 0; }
            ke9[t9] = ker4[((ka * 3 + kb) * 3 + kc) * 32 + c * 4 + q];
        }
#pragma unroll
        for (int dy = 0; dy < 3; ++dy)
#pragma unroll
            for (int dx = 0; dx < 3; ++dx) {
                float4 kv = ke9[dy * 3 + dx];
                int base = ((k2 * 3 + dy) * 66 + slot + dx) * 8 + c;
#pragma unroll
                for (int i = 0; i < 8; ++i) {
                    float v = xsf[base + i * 64];   // conflict-free (R8-measured 0)
                    acc[i].x = fminf(acc[i].x, v - kv.x);
                    acc[i].y = fminf(acc[i].y, v - kv.y);
                    acc[i].z = fminf(acc[i].z, v - kv.z);
                    acc[i].w = fminf(acc[i].w, v - kv.w);
                }
            }
    }

    float4* ero4 = (float4*)ero;
    const int row = (b * 4 + g) * HH + h;
    const size_t obase =
        ((size_t)row * PADW + slot + (PADW == 66 ? 1 : 0)) * 32 + c * 4 + q;
#pragma unroll
    for (int i = 0; i < 8; ++i)
        ero4[obase + (size_t)i * 256] = acc[i];

    if (PADW == 66) {   // -inf border columns wp=0, wp=65 (32 f4 each)
        const float4 ninf = make_float4(NEG_INF, NEG_INF, NEG_INF, NEG_INF);
        if (tid < 32)
            ero4[(size_t)row * 66 * 32 + tid] = ninf;
        else if (tid < 64)
            ero4[((size_t)row * 66 + 65) * 32 + (tid - 32)] = ninf;
    }
}

// ======================= kernel 2: dilation =========================
// block = (b,j,h); thread = (slot,c,q); 8 px (w = slot+8i); c-sum via xor-shuffle.
template <int PADW>
__global__ __launch_bounds__(256) void dilate_t(const float* __restrict__ ero,
                                                const float* __restrict__ ker,
                                                float* __restrict__ out) {
    const int tid = threadIdx.x;
    const int q = tid & 3;
    const int c = (tid >> 2) & 7;
    const int slot = tid >> 5;
    const int h = blockIdx.x & 63;
    const int j = (blockIdx.x >> 6) & 3;
    const int b = blockIdx.x >> 8;

    const float4* ker4 = (const float4*)ker;
    const float4* ero4 = (const float4*)ero;

    float4 acc[8];
#pragma unroll
    for (int i = 0; i < 8; ++i)
        acc[i] = make_float4(NEG_INF, NEG_INF, NEG_INF, NEG_INF);

#define UPDMAX(A, E, K) A.x = fmaxf(A.x, (E).x + (K).x); A.y = fmaxf(A.y, (E).y + (K).y); \
                        A.z = fmaxf(A.z, (E).z + (K).z); A.w = fmaxf(A.w, (E).w + (K).w)

#pragma unroll
    for (int k = 0; k < 3; ++k) {
        const int gsrc = (j + k + 3) & 3;
        float4 kd9[9];
#pragma unroll
        for (int t9 = 0; t9 < 9; ++t9) {
            int dy = t9 / 3, dx = t9 % 3;
            int i, jj;
            ROT_G(j, dy, dx, i, jj);
            kd9[t9] = ker4[((i * 3 + jj) * 3 + k) * 32 + c * 4 + q];
        }
        const size_t pb = (size_t)(b * 4 + gsrc) * HH * PADW * 32 + c * 4 + q;
#pragma unroll
        for (int dy = 0; dy < 3; ++dy) {
            const int hh = h + dy - 1;
            if ((unsigned)hh >= HH) continue;   // wave-uniform branch
            const size_t rowb = pb + (size_t)hh * PADW * 32;
            if (PADW == 66) {
#pragma unroll
                for (int i = 0; i < 8; ++i) {
                    const size_t base = rowb + (size_t)(slot + 8 * i) * 32;
                    float4 e0 = ero4[base];          // wp = w .. taps at imm offsets
                    float4 e1 = ero4[base + 32];
                    float4 e2 = ero4[base + 64];
                    UPDMAX(acc[i], e0, kd9[dy * 3 + 0]);
                    UPDMAX(acc[i], e1, kd9[dy * 3 + 1]);
                    UPDMAX(acc[i], e2, kd9[dy * 3 + 2]);
                }
            } else {
#pragma unroll
                for (int i = 0; i < 8; ++i) {
                    const int w = slot + 8 * i;
#pragma unroll
                    for (int dx = 0; dx < 3; ++dx) {
                        const int ww = w + dx - 1;
                        if ((unsigned)ww >= WW) continue;
                        float4 e = ero4[rowb + (size_t)ww * 32];
                        UPDMAX(acc[i], e, kd9[dy * 3 + dx]);
                    }
                }
            }
        }
    }
#undef UPDMAX

    // sum over c (c = lane bits 2-4 within the 64-lane wave)
#pragma unroll
    for (int i = 0; i < 8; ++i) {
#pragma unroll
        for (int off = 4; off <= 16; off <<= 1) {
            acc[i].x += __shfl_xor(acc[i].x, off, 64);
            acc[i].y += __shfl_xor(acc[i].y, off, 64);
            acc[i].z += __shfl_xor(acc[i].z, off, 64);
            acc[i].w += __shfl_xor(acc[i].w, off, 64);
        }
    }
    if (c == 0) {
        const int bjh = (b * 4 + j) * HH + h;
        float4* out4 = (float4*)out;
#pragma unroll
        for (int i = 0; i < 8; ++i)
            out4[((size_t)bjh * WW + slot + 8 * i) * 4 + q] = acc[i];
    }
}

// ============== fallback: PASSED fused kernel (258 us, R5) ==============
__global__ __launch_bounds__(256, 3) void opening_fused_fb(
    const float* __restrict__ x, const float* __restrict__ ker, float* __restrict__ out)
{
    __shared__ __align__(16) float xs[8 * 4 * 144];
    __shared__ float4 es4[4 * 4 * 100];
    __shared__ float4 ke4[27 * 4 * 4];
    __shared__ float4 kd4[9 * 4 * 4];

    const int tid = threadIdx.x;
    const int tileX = blockIdx.x & 7;
    const int tileY = (blockIdx.x >> 3) & 7;
    const int j = (blockIdx.x >> 6) & 3;
    const int b = blockIdx.x >> 8;
    const float4* ker4 = (const float4*)ker;
    const float4* x4 = (const float4*)x;

    for (int t = tid; t < 1152; t += 256) {
        int q01 = t & 1;
        int cell = t >> 1;
        int g = cell / 144;
        int rem = cell - g * 144;
        int r = rem / 12;
        int s = rem - r * 12;
        int h = tileY * 8 - 2 + r;
        int w = tileX * 8 - 2 + s;
        float4 v;
        if ((unsigned)h < HH && (unsigned)w < WW)
            v = x4[(((b * 4 + g) * HH + h) * WW + w) * 2 + q01];
        else
            v = make_float4(POS_INF, POS_INF, POS_INF, POS_INF);
        int c0 = q01 * 4;
        xs[((c0 + 0) * 4 + g) * 144 + rem] = v.x;
        xs[((c0 + 1) * 4 + g) * 144 + rem] = v.y;
        xs[((c0 + 2) * 4 + g) * 144 + rem] = v.z;
        xs[((c0 + 3) * 4 + g) * 144 + rem] = v.w;
    }
    __syncthreads();

    const int q_o = tid & 3;
    const int ox = (tid >> 2) & 7;
    const int oy = tid >> 5;

    float4 acc[8];
#pragma unroll
    for (int c = 0; c < 8; ++c)
        acc[c] = make_float4(NEG_INF, NEG_INF, NEG_INF, NEG_INF);

    for (int k = 0; k < 3; ++k) {
        const int gsrc = (j + k + 3) & 3;
#pragma unroll
        for (int cg = 0; cg < 2; ++cg) {
            for (int t = tid; t < 576; t += 256) {
                if (t < 432) {
                    int q = t & 3;
                    int c4 = (t >> 2) & 3;
                    int tap = t >> 4;
                    int k2 = tap % 3;
                    int dxdy = tap / 3;
                    int dx = dxdy % 3;
                    int dy = dxdy / 3;
                    int a0 = 2 - dy, b0 = 2 - dx;
                    int i, jj;
                    ROT_G(gsrc, a0, b0, i, jj);
                    int ka, kb, kc;
                    if (k2 == 0)      { ka = 2 - jj; kb = i;      kc = 2; }
                    else if (k2 == 1) { ka = i;      kb = jj;     kc = 1; }
                    else              { ka = jj;     kb = 2 - i;  kc = 0; }
                    int c = cg * 4 + c4;
                    ke4[t] = ker4[((ka * 3 + kb) * 3 + kc) * 32 + c * 4 + q];
                } else {
                    int u = t - 432;
                    int q = u & 3;
                    int c4 = (u >> 2) & 3;
                    int dydx = u >> 4;
                    int dx = dydx % 3;
                    int dy = dydx / 3;
                    int i, jj;
                    ROT_G(j, dy, dx, i, jj);
                    int c = cg * 4 + c4;
                    kd4[u] = ker4[((i * 3 + jj) * 3 + k) * 32 + c * 4 + q];
                }
            }
            __syncthreads();

            for (int it = 0; it < 2; ++it) {
                int id = tid + (it << 8);
                int c4 = id >> 7;
                int p = id & 127;
                if (p >= 100) continue;
                int ey = (p * 205) >> 11;
                int ex = p - ey * 10;
                int h_es = tileY * 8 - 1 + ey;
                int w_es = tileX * 8 - 1 + ex;
                float4 b0, b1, b2, b3;
                if ((unsigned)h_es < HH && (unsigned)w_es < WW) {
                    b0 = b1 = b2 = b3 = make_float4(POS_INF, POS_INF, POS_INF, POS_INF);
                    int c = cg * 4 + c4;
#pragma unroll
                    for (int k2 = 0; k2 < 3; ++k2) {
                        int g2 = (gsrc + k2 + 3) & 3;
                        int base = (c * 4 + g2) * 144 + ey * 12 + ex;
#pragma unroll
                        for (int dy = 0; dy < 3; ++dy)
#pragma unroll
                            for (int dx = 0; dx < 3; ++dx) {
                                float v = xs[base + dy * 12 + dx];
                                const float4* kk = &ke4[(((dy * 3 + dx) * 3 + k2) * 4 + c4) * 4];
                                float4 kv;
                                kv = kk[0];
                                b0.x = fminf(b0.x, v - kv.x); b0.y = fminf(b0.y, v - kv.y);
                                b0.z = fminf(b0.z, v - kv.z); b0.w = fminf(b0.w, v - kv.w);
                                kv = kk[1];
                                b1.x = fminf(b1.x, v - kv.x); b1.y = fminf(b1.y, v - kv.y);
                                b1.z = fminf(b1.z, v - kv.z); b1.w = fminf(b1.w, v - kv.w);
                                kv = kk[2];
                                b2.x = fminf(b2.x, v - kv.x); b2.y = fminf(b2.y, v - kv.y);
                                b2.z = fminf(b2.z, v - kv.z); b2.w = fminf(b2.w, v - kv.w);
                                kv = kk[3];
                                b3.x = fminf(b3.x, v - kv.x); b3.y = fminf(b3.y, v - kv.y);
                                b3.z = fminf(b3.z, v - kv.z); b3.w = fminf(b3.w, v - kv.w);
                            }
                    }
                } else {
                    b0 = b1 = b2 = b3 = make_float4(NEG_INF, NEG_INF, NEG_INF, NEG_INF);
                }
                int eb = (c4 * 4) * 100 + p;
                es4[eb] = b0; es4[eb + 100] = b1; es4[eb + 200] = b2; es4[eb + 300] = b3;
            }
            __syncthreads();

#pragma unroll
            for (int c4 = 0; c4 < 4; ++c4) {
                float4 a = acc[cg * 4 + c4];
#pragma unroll
                for (int dy = 0; dy < 3; ++dy)
#pragma unroll
                    for (int dx = 0; dx < 3; ++dx) {
                        int pos = (oy + dy) * 10 + (ox + dx);
                        float4 e = es4[(c4 * 4 + q_o) * 100 + pos];
                        float4 kv = kd4[(dy * 3 + dx) * 16 + c4 * 4 + q_o];
                        a.x = fmaxf(a.x, e.x + kv.x);
                        a.y = fmaxf(a.y, e.y + kv.y);
                        a.z = fmaxf(a.z, e.z + kv.z);
                        a.w = fmaxf(a.w, e.w + kv.w);
                    }
                acc[cg * 4 + c4] = a;
            }
            __syncthreads();
        }
    }

    float4 s = acc[0];
#pragma unroll
    for (int c = 1; c < 8; ++c) {
        s.x += acc[c].x; s.y += acc[c].y; s.z += acc[c].z; s.w += acc[c].w;
    }
    const int h = tileY * 8 + oy;
    const int w = tileX * 8 + ox;
    ((float4*)out)[(((b * 4 + j) * HH + h) * WW + w) * 4 + q_o] = s;
}

extern "C" void kernel_launch(void* const* d_in, const int* in_sizes, int n_in,
                              void* d_out, int out_size, void* d_ws, size_t ws_size,
                              hipStream_t stream) {
    const float* x = (const float*)d_in[0];
    const float* ker = (const float*)d_in[1];
    float* out = (float*)d_out;

    const size_t padded_bytes = (size_t)4 * 4 * HH * 66 * 32 * 16;   // 34,603,008
    const size_t plain_bytes  = (size_t)4 * 4 * HH * 64 * 32 * 16;   // 33,554,432

    if (ws_size >= padded_bytes) {
        float* ero = (float*)d_ws;
        erode_t<66><<<1024, 256, 0, stream>>>(x, ker, ero);
        dilate_t<66><<<1024, 256, 0, stream>>>(ero, ker, out);
    } else if (ws_size >= plain_bytes) {
        float* ero = (float*)d_ws;
        erode_t<64><<<1024, 256, 0, stream>>>(x, ker, ero);
        dilate_t<64><<<1024, 256, 0, stream>>>(ero, ker, out);
    } else {
        opening_fused_fb<<<1024, 256, 0, stream>>>(x, ker, out);
    }
}

// Round 11
// 105.266 us; speedup vs baseline: 9.5658x; 1.2711x over previous
//
#include <hip/hip_runtime.h>

// OpeningP4: x [4,4,64,64,8] f32, kernel [3,3,3,8,16] f32 -> out [4,4,64,64,16] f32.
// v11 = R10 design with the f16 path rewritten on _Float16 ext-vectors
// (ROCm 7.2 has no __hmax2; __builtin_elementwise_max -> v_pk_max_f16).
//  - ero intermediate f16: 33.5 -> 17.3 MB
//  - dilate h-strip streaming: 216 -> 90 loads/thread, packed f16 max/add
// Erosion compute + rotation algebra verbatim from PASSED rounds (absmax 0.0625).

#define HH 64
#define WW 64
#define NEG_INF (-__builtin_inff())
#define POS_INF (__builtin_inff())

#define ROT_G(G, A, B, I, J) do { switch (G) { \
    case 0:  I = (A);     J = (B);     break; \
    case 1:  I = (B);     J = 2 - (A); break; \
    case 2:  I = 2 - (A); J = 2 - (B); break; \
    default: I = 2 - (B); J = (A);     break; } } while (0)

typedef _Float16 hv4 __attribute__((ext_vector_type(4)));   // 8 B, v_pk_* pairs

__device__ __forceinline__ hv4 f4_to_hv4(float4 v) {
    hv4 r;
    r.x = (_Float16)v.x; r.y = (_Float16)v.y;
    r.z = (_Float16)v.z; r.w = (_Float16)v.w;
    return r;
}

// ======================= kernel 1: erosion (f32 math, f16 store) ==================
// block = (b,g,h); thread = (slot,c,q); pixels w = slot + 8i.
// ero layout (hv4 elems): ((bg*64+h)*66 + wp)*32 + c*4 + q, wp = w+1, -inf borders.
__global__ __launch_bounds__(256) void erode_t(const float* __restrict__ x,
                                               const float* __restrict__ ker,
                                               hv4* __restrict__ ero) {
    __shared__ float4 xs4[1188];   // [p][r][wp0..65][q01] ; 19008 B

    const int tid = threadIdx.x;
    const int h = blockIdx.x & 63;
    const int g = (blockIdx.x >> 6) & 3;
    const int b = blockIdx.x >> 8;

    const float4* x4 = (const float4*)x;
    const float4* ker4 = (const float4*)ker;

    for (int t = tid; t < 1188; t += 256) {
        int q01 = t & 1;
        int u = t >> 1;
        int wp = u % 66;
        int v = u / 66;
        int r = v % 3;
        int p = v / 3;
        int g2 = (g + p + 3) & 3;
        int h2 = h - 1 + r;
        int w2 = wp - 1;
        float4 vv;
        if ((unsigned)h2 < HH && (unsigned)w2 < WW)
            vv = x4[(((b * 4 + g2) * HH + h2) * WW + w2) * 2 + q01];
        else
            vv = make_float4(POS_INF, POS_INF, POS_INF, POS_INF);
        xs4[((p * 3 + r) * 66 + wp) * 2 + q01] = vv;
    }
    __syncthreads();

    const int q = tid & 3;
    const int c = (tid >> 2) & 7;
    const int slot = tid >> 5;
    const float* xsf = (const float*)xs4;

    float4 acc[8];
#pragma unroll
    for (int i = 0; i < 8; ++i)
        acc[i] = make_float4(POS_INF, POS_INF, POS_INF, POS_INF);

#pragma unroll
    for (int k2 = 0; k2 < 3; ++k2) {
        float4 ke9[9];
#pragma unroll
        for (int t9 = 0; t9 < 9; ++t9) {
            int dy = t9 / 3, dx = t9 % 3;
            int a0 = 2 - dy, b0 = 2 - dx;
            int i, jj;
            ROT_G(g, a0, b0, i, jj);
            int ka, kb, kc;
            if (k2 == 0)      { ka = 2 - jj; kb = i;      kc = 2; }
            else if (k2 == 1) { ka = i;      kb = jj;     kc = 1; }
            else              { ka = jj;     kb = 2 - i;  kc = 0; }
            ke9[t9] = ker4[((ka * 3 + kb) * 3 + kc) * 32 + c * 4 + q];
        }
#pragma unroll
        for (int dy = 0; dy < 3; ++dy)
#pragma unroll
            for (int dx = 0; dx < 3; ++dx) {
                float4 kv = ke9[dy * 3 + dx];
                int base = ((k2 * 3 + dy) * 66 + slot + dx) * 8 + c;
#pragma unroll
                for (int i = 0; i < 8; ++i) {
                    float v = xsf[base + i * 64];   // conflict-free (R8-measured 0)
                    acc[i].x = fminf(acc[i].x, v - kv.x);
                    acc[i].y = fminf(acc[i].y, v - kv.y);
                    acc[i].z = fminf(acc[i].z, v - kv.z);
                    acc[i].w = fminf(acc[i].w, v - kv.w);
                }
            }
    }

    const int row = (b * 4 + g) * HH + h;
    const size_t obase = ((size_t)row * 66 + slot + 1) * 32 + c * 4 + q;
#pragma unroll
    for (int i = 0; i < 8; ++i)
        ero[obase + (size_t)i * 256] = f4_to_hv4(acc[i]);

    // -inf border columns wp=0, wp=65 (32 hv4 each)
    const hv4 ninf = {(_Float16)NEG_INF, (_Float16)NEG_INF,
                      (_Float16)NEG_INF, (_Float16)NEG_INF};
    if (tid < 32)
        ero[(size_t)row * 66 * 32 + tid] = ninf;
    else if (tid < 64)
        ero[((size_t)row * 66 + 65) * 32 + (tid - 32)] = ninf;
}

// ======================= kernel 2: dilation (packed f16) ==========================
// block = (b,j,hs,ws); thread = (slot,c,q); w = ws*8+slot, out rows hs*8..hs*8+7.
// Each ero row (10 per strip) loaded once (3 taps) feeds 3 out rows.
__global__ __launch_bounds__(256) void dilate_t(const hv4* __restrict__ ero,
                                                const float* __restrict__ ker,
                                                float* __restrict__ out) {
    const int tid = threadIdx.x;
    const int q = tid & 3;
    const int c = (tid >> 2) & 7;
    const int slot = tid >> 5;
    const int ws = blockIdx.x & 7;
    const int hs = (blockIdx.x >> 3) & 7;
    const int j = (blockIdx.x >> 6) & 3;
    const int b = blockIdx.x >> 8;
    const int w = ws * 8 + slot;

    const float4* ker4 = (const float4*)ker;

    const hv4 ninf = {(_Float16)NEG_INF, (_Float16)NEG_INF,
                      (_Float16)NEG_INF, (_Float16)NEG_INF};
    hv4 acc[8];
#pragma unroll
    for (int r = 0; r < 8; ++r)
        acc[r] = ninf;

#pragma unroll
    for (int k = 0; k < 3; ++k) {
        const int gsrc = (j + k + 3) & 3;
        hv4 kd9[9];
#pragma unroll
        for (int t9 = 0; t9 < 9; ++t9) {
            int dy = t9 / 3, dx = t9 % 3;
            int i, jj;
            ROT_G(j, dy, dx, i, jj);
            kd9[t9] = f4_to_hv4(ker4[((i * 3 + jj) * 3 + k) * 32 + c * 4 + q]);
        }
        // taps at wp = w, w+1, w+2 -> hv4 offsets +0, +32, +64
        const size_t pb = ((size_t)(b * 4 + gsrc) * HH * 66 + w) * 32 + c * 4 + q;
#pragma unroll
        for (int ei = 0; ei < 10; ++ei) {
            const int er = hs * 8 - 1 + ei;
            if ((unsigned)er >= HH) continue;           // wave-uniform
            const size_t rb = pb + (size_t)er * 66 * 32;
            hv4 e0 = ero[rb];
            hv4 e1 = ero[rb + 32];
            hv4 e2 = ero[rb + 64];
#pragma unroll
            for (int dy = 0; dy < 3; ++dy) {
                const int r = ei - 2 + dy;               // out local row: er-(h)-(dy-1)... see note
                // out row ho = er - (dy-1); local r = ho - hs*8 = ei - dy
                const int rr = ei - dy;
                if ((unsigned)rr >= 8) continue;
                acc[rr] = __builtin_elementwise_max(acc[rr], e0 + kd9[dy * 3 + 0]);
                acc[rr] = __builtin_elementwise_max(acc[rr], e1 + kd9[dy * 3 + 1]);
                acc[rr] = __builtin_elementwise_max(acc[rr], e2 + kd9[dy * 3 + 2]);
                (void)r;
            }
        }
    }

    // c-sum in f32 via xor-shuffle (c = lane bits 2..4), then store
    float4* out4 = (float4*)out;
    const int bjbase = (b * 4 + j) * HH + hs * 8;
#pragma unroll
    for (int r = 0; r < 8; ++r) {
        float4 s = make_float4((float)acc[r].x, (float)acc[r].y,
                               (float)acc[r].z, (float)acc[r].w);
#pragma unroll
        for (int off = 4; off <= 16; off <<= 1) {
            s.x += __shfl_xor(s.x, off, 64);
            s.y += __shfl_xor(s.y, off, 64);
            s.z += __shfl_xor(s.z, off, 64);
            s.w += __shfl_xor(s.w, off, 64);
        }
        if (c == 0)
            out4[((size_t)(bjbase + r) * WW + w) * 4 + q] = s;
    }
}

// ============== fallback: PASSED fused kernel (258 us, R5) ==============
__global__ __launch_bounds__(256, 3) void opening_fused_fb(
    const float* __restrict__ x, const float* __restrict__ ker, float* __restrict__ out)
{
    __shared__ __align__(16) float xs[8 * 4 * 144];
    __shared__ float4 es4[4 * 4 * 100];
    __shared__ float4 ke4[27 * 4 * 4];
    __shared__ float4 kd4[9 * 4 * 4];

    const int tid = threadIdx.x;
    const int tileX = blockIdx.x & 7;
    const int tileY = (blockIdx.x >> 3) & 7;
    const int j = (blockIdx.x >> 6) & 3;
    const int b = blockIdx.x >> 8;
    const float4* ker4 = (const float4*)ker;
    const float4* x4 = (const float4*)x;

    for (int t = tid; t < 1152; t += 256) {
        int q01 = t & 1;
        int cell = t >> 1;
        int g = cell / 144;
        int rem = cell - g * 144;
        int r = rem / 12;
        int s = rem - r * 12;
        int h = tileY * 8 - 2 + r;
        int w = tileX * 8 - 2 + s;
        float4 v;
        if ((unsigned)h < HH && (unsigned)w < WW)
            v = x4[(((b * 4 + g) * HH + h) * WW + w) * 2 + q01];
        else
            v = make_float4(POS_INF, POS_INF, POS_INF, POS_INF);
        int c0 = q01 * 4;
        xs[((c0 + 0) * 4 + g) * 144 + rem] = v.x;
        xs[((c0 + 1) * 4 + g) * 144 + rem] = v.y;
        xs[((c0 + 2) * 4 + g) * 144 + rem] = v.z;
        xs[((c0 + 3) * 4 + g) * 144 + rem] = v.w;
    }
    __syncthreads();

    const int q_o = tid & 3;
    const int ox = (tid >> 2) & 7;
    const int oy = tid >> 5;

    float4 acc[8];
#pragma unroll
    for (int c = 0; c < 8; ++c)
        acc[c] = make_float4(NEG_INF, NEG_INF, NEG_INF, NEG_INF);

    for (int k = 0; k < 3; ++k) {
        const int gsrc = (j + k + 3) & 3;
#pragma unroll
        for (int cg = 0; cg < 2; ++cg) {
            for (int t = tid; t < 576; t += 256) {
                if (t < 432) {
                    int q = t & 3;
                    int c4 = (t >> 2) & 3;
                    int tap = t >> 4;
                    int k2 = tap % 3;
                    int dxdy = tap / 3;
                    int dx = dxdy % 3;
                    int dy = dxdy / 3;
                    int a0 = 2 - dy, b0 = 2 - dx;
                    int i, jj;
                    ROT_G(gsrc, a0, b0, i, jj);
                    int ka, kb, kc;
                    if (k2 == 0)      { ka = 2 - jj; kb = i;      kc = 2; }
                    else if (k2 == 1) { ka = i;      kb = jj;     kc = 1; }
                    else              { ka = jj;     kb = 2 - i;  kc = 0; }
                    int c = cg * 4 + c4;
                    ke4[t] = ker4[((ka * 3 + kb) * 3 + kc) * 32 + c * 4 + q];
                } else {
                    int u = t - 432;
                    int q = u & 3;
                    int c4 = (u >> 2) & 3;
                    int dydx = u >> 4;
                    int dx = dydx % 3;
                    int dy = dydx / 3;
                    int i, jj;
                    ROT_G(j, dy, dx, i, jj);
                    int c = cg * 4 + c4;
                    kd4[u] = ker4[((i * 3 + jj) * 3 + k) * 32 + c * 4 + q];
                }
            }
            __syncthreads();

            for (int it = 0; it < 2; ++it) {
                int id = tid + (it << 8);
                int c4 = id >> 7;
                int p = id & 127;
                if (p >= 100) continue;
                int ey = (p * 205) >> 11;
                int ex = p - ey * 10;
                int h_es = tileY * 8 - 1 + ey;
                int w_es = tileX * 8 - 1 + ex;
                float4 b0, b1, b2, b3;
                if ((unsigned)h_es < HH && (unsigned)w_es < WW) {
                    b0 = b1 = b2 = b3 = make_float4(POS_INF, POS_INF, POS_INF, POS_INF);
                    int c = cg * 4 + c4;
#pragma unroll
                    for (int k2 = 0; k2 < 3; ++k2) {
                        int g2 = (gsrc + k2 + 3) & 3;
                        int base = (c * 4 + g2) * 144 + ey * 12 + ex;
#pragma unroll
                        for (int dy = 0; dy < 3; ++dy)
#pragma unroll
                            for (int dx = 0; dx < 3; ++dx) {
                                float v = xs[base + dy * 12 + dx];
                                const float4* kk = &ke4[(((dy * 3 + dx) * 3 + k2) * 4 + c4) * 4];
                                float4 kv;
                                kv = kk[0];
                                b0.x = fminf(b0.x, v - kv.x); b0.y = fminf(b0.y, v - kv.y);
                                b0.z = fminf(b0.z, v - kv.z); b0.w = fminf(b0.w, v - kv.w);
                                kv = kk[1];
                                b1.x = fminf(b1.x, v - kv.x); b1.y = fminf(b1.y, v - kv.y);
                                b1.z = fminf(b1.z, v - kv.z); b1.w = fminf(b1.w, v - kv.w);
                                kv = kk[2];
                                b2.x = fminf(b2.x, v - kv.x); b2.y = fminf(b2.y, v - kv.y);
                                b2.z = fminf(b2.z, v - kv.z); b2.w = fminf(b2.w, v - kv.w);
                                kv = kk[3];
                                b3.x = fminf(b3.x, v - kv.x); b3.y = fminf(b3.y, v - kv.y);
                                b3.z = fminf(b3.z, v - kv.z); b3.w = fminf(b3.w, v - kv.w);
                            }
                    }
                } else {
                    b0 = b1 = b2 = b3 = make_float4(NEG_INF, NEG_INF, NEG_INF, NEG_INF);
                }
                int eb = (c4 * 4) * 100 + p;
                es4[eb] = b0; es4[eb + 100] = b1; es4[eb + 200] = b2; es4[eb + 300] = b3;
            }
            __syncthreads();

#pragma unroll
            for (int c4 = 0; c4 < 4; ++c4) {
                float4 a = acc[cg * 4 + c4];
#pragma unroll
                for (int dy = 0; dy < 3; ++dy)
#pragma unroll
                    for (int dx = 0; dx < 3; ++dx) {
                        int pos = (oy + dy) * 10 + (ox + dx);
                        float4 e = es4[(c4 * 4 + q_o) * 100 + pos];
                        float4 kv = kd4[(dy * 3 + dx) * 16 + c4 * 4 + q_o];
                        a.x = fmaxf(a.x, e.x + kv.x);
                        a.y = fmaxf(a.y, e.y + kv.y);
                        a.z = fmaxf(a.z, e.z + kv.z);
                        a.w = fmaxf(a.w, e.w + kv.w);
                    }
                acc[cg * 4 + c4] = a;
            }
            __syncthreads();
        }
    }

    float4 s = acc[0];
#pragma unroll
    for (int c = 1; c < 8; ++c) {
        s.x += acc[c].x; s.y += acc[c].y; s.z += acc[c].z; s.w += acc[c].w;
    }
    const int h = tileY * 8 + oy;
    const int w = tileX * 8 + ox;
    ((float4*)out)[(((b * 4 + j) * HH + h) * WW + w) * 4 + q_o] = s;
}

extern "C" void kernel_launch(void* const* d_in, const int* in_sizes, int n_in,
                              void* d_out, int out_size, void* d_ws, size_t ws_size,
                              hipStream_t stream) {
    const float* x = (const float*)d_in[0];
    const float* ker = (const float*)d_in[1];
    float* out = (float*)d_out;

    const size_t ero_f16_bytes = (size_t)16 * HH * 66 * 32 * 8;   // 17,301,504

    if (ws_size >= ero_f16_bytes) {
        hv4* ero = (hv4*)d_ws;
        erode_t<<<1024, 256, 0, stream>>>(x, ker, ero);
        dilate_t<<<1024, 256, 0, stream>>>(ero, ker, out);
    } else {
        opening_fused_fb<<<1024, 256, 0, stream>>>(x, ker, out);
    }
}

// Round 12
// 91.489 us; speedup vs baseline: 11.0063x; 1.1506x over previous
//
#include <hip/hip_runtime.h>

// OpeningP4: x [4,4,64,64,8] f32, kernel [3,3,3,8,16] f32 -> out [4,4,64,64,16] f32.
// v12 = R11 (105us PASSED) + erode LDS-issue fix:
//  - thread px remapped to consecutive w = slot*8+i -> 27 ds_read_b128 instead of
//    216 ds_read_b32 per thread (xs row stride 68 floats: 16B-aligned, <=2-way banks)
// dilate + f16 ero layout unchanged from R11. NOTE: harness poison-fill of d_ws
// (268MB, 44us) is a fixed timed overhead — visible as fillBufferAligned in rocprof.
// Rotation algebra verbatim from PASSED rounds (absmax 0.0625).

#define HH 64
#define WW 64
#define NEG_INF (-__builtin_inff())
#define POS_INF (__builtin_inff())

#define ROT_G(G, A, B, I, J) do { switch (G) { \
    case 0:  I = (A);     J = (B);     break; \
    case 1:  I = (B);     J = 2 - (A); break; \
    case 2:  I = 2 - (A); J = 2 - (B); break; \
    default: I = 2 - (B); J = (A);     break; } } while (0)

typedef _Float16 hv4 __attribute__((ext_vector_type(4)));   // 8 B, v_pk_* pairs

__device__ __forceinline__ hv4 f4_to_hv4(float4 v) {
    hv4 r;
    r.x = (_Float16)v.x; r.y = (_Float16)v.y;
    r.z = (_Float16)v.z; r.w = (_Float16)v.w;
    return r;
}

// ======================= kernel 1: erosion (f32 math, f16 store) ==================
// block = (b,g,h); thread = (slot,c,q); pixels w = slot*8 + i, i=0..7 (consecutive).
// ero layout (hv4 elems): ((bg*64+h)*66 + wp)*32 + c*4 + q, wp = w+1, -inf borders.
__global__ __launch_bounds__(256) void erode_t(const float* __restrict__ x,
                                               const float* __restrict__ ker,
                                               hv4* __restrict__ ero) {
    // [p*3+r][c][wp0..67]: stride 68 -> c*68 is 16B-aligned (68%4==0), banks <=2-way
    __shared__ __align__(16) float xs[9 * 8 * 68];   // 19584 B

    const int tid = threadIdx.x;
    const int h = blockIdx.x & 63;
    const int g = (blockIdx.x >> 6) & 3;
    const int b = blockIdx.x >> 8;

    const float4* x4 = (const float4*)x;
    const float4* ker4 = (const float4*)ker;

    // stage 3 planes x[(g+p-1)&3], rows h-1..h+1, cols -1..64 (wp 0..65), OOB=+inf
    for (int t = tid; t < 1188; t += 256) {
        int q01 = t & 1;
        int u = t >> 1;
        int wp = u % 66;
        int v = u / 66;
        int r = v % 3;
        int p = v / 3;
        int g2 = (g + p + 3) & 3;
        int h2 = h - 1 + r;
        int w2 = wp - 1;
        float4 vv;
        if ((unsigned)h2 < HH && (unsigned)w2 < WW)
            vv = x4[(((b * 4 + g2) * HH + h2) * WW + w2) * 2 + q01];
        else
            vv = make_float4(POS_INF, POS_INF, POS_INF, POS_INF);
        int rowb = (p * 3 + r) * 8 + q01 * 4;
        xs[(rowb + 0) * 68 + wp] = vv.x;
        xs[(rowb + 1) * 68 + wp] = vv.y;
        xs[(rowb + 2) * 68 + wp] = vv.z;
        xs[(rowb + 3) * 68 + wp] = vv.w;
    }
    __syncthreads();

    const int q = tid & 3;
    const int c = (tid >> 2) & 7;
    const int slot = tid >> 5;
    const float4* xs4 = (const float4*)xs;

    float4 acc[8];
#pragma unroll
    for (int i = 0; i < 8; ++i)
        acc[i] = make_float4(POS_INF, POS_INF, POS_INF, POS_INF);

#pragma unroll
    for (int k2 = 0; k2 < 3; ++k2) {
        // KE_g[dy,dx,k2,c,f4=q] in registers: 9 coalesced 1KB wave reads (L1-hot)
        float4 ke9[9];
#pragma unroll
        for (int t9 = 0; t9 < 9; ++t9) {
            int dy = t9 / 3, dx = t9 % 3;
            int a0 = 2 - dy, b0 = 2 - dx;
            int i, jj;
            ROT_G(g, a0, b0, i, jj);
            int ka, kb, kc;
            if (k2 == 0)      { ka = 2 - jj; kb = i;      kc = 2; }
            else if (k2 == 1) { ka = i;      kb = jj;     kc = 1; }
            else              { ka = jj;     kb = 2 - i;  kc = 0; }
            ke9[t9] = ker4[((ka * 3 + kb) * 3 + kc) * 32 + c * 4 + q];
        }
#pragma unroll
        for (int dy = 0; dy < 3; ++dy) {
            // 12-float window (wp = slot*8 .. slot*8+11) as 3x ds_read_b128
            const int base4 = ((k2 * 3 + dy) * 8 + c) * 17 + slot * 2;
            float4 xa = xs4[base4];
            float4 xb = xs4[base4 + 1];
            float4 xc = xs4[base4 + 2];
            float xw[12] = {xa.x, xa.y, xa.z, xa.w,
                            xb.x, xb.y, xb.z, xb.w,
                            xc.x, xc.y, xc.z, xc.w};
#pragma unroll
            for (int dx = 0; dx < 3; ++dx) {
                float4 kv = ke9[dy * 3 + dx];
#pragma unroll
                for (int i = 0; i < 8; ++i) {
                    float v = xw[i + dx];   // tap wp = slot*8 + i + dx
                    acc[i].x = fminf(acc[i].x, v - kv.x);
                    acc[i].y = fminf(acc[i].y, v - kv.y);
                    acc[i].z = fminf(acc[i].z, v - kv.z);
                    acc[i].w = fminf(acc[i].w, v - kv.w);
                }
            }
        }
    }

    // store: wp = slot*8 + i + 1; lanes (q,c) -> 256B contiguous per (slot,i)
    const int row = (b * 4 + g) * HH + h;
    const size_t obase = ((size_t)row * 66 + slot * 8 + 1) * 32 + c * 4 + q;
#pragma unroll
    for (int i = 0; i < 8; ++i)
        ero[obase + (size_t)i * 32] = f4_to_hv4(acc[i]);

    // -inf border columns wp=0, wp=65 (32 hv4 each)
    const hv4 ninf = {(_Float16)NEG_INF, (_Float16)NEG_INF,
                      (_Float16)NEG_INF, (_Float16)NEG_INF};
    if (tid < 32)
        ero[(size_t)row * 66 * 32 + tid] = ninf;
    else if (tid < 64)
        ero[((size_t)row * 66 + 65) * 32 + (tid - 32)] = ninf;
}

// ======================= kernel 2: dilation (packed f16) ==========================
// block = (b,j,hs,ws); thread = (slot,c,q); w = ws*8+slot, out rows hs*8..hs*8+7.
// Each ero row (10 per strip) loaded once (3 taps) feeds 3 out rows.
__global__ __launch_bounds__(256) void dilate_t(const hv4* __restrict__ ero,
                                                const float* __restrict__ ker,
                                                float* __restrict__ out) {
    const int tid = threadIdx.x;
    const int q = tid & 3;
    const int c = (tid >> 2) & 7;
    const int slot = tid >> 5;
    const int ws = blockIdx.x & 7;
    const int hs = (blockIdx.x >> 3) & 7;
    const int j = (blockIdx.x >> 6) & 3;
    const int b = blockIdx.x >> 8;
    const int w = ws * 8 + slot;

    const float4* ker4 = (const float4*)ker;

    const hv4 ninf = {(_Float16)NEG_INF, (_Float16)NEG_INF,
                      (_Float16)NEG_INF, (_Float16)NEG_INF};
    hv4 acc[8];
#pragma unroll
    for (int r = 0; r < 8; ++r)
        acc[r] = ninf;

#pragma unroll
    for (int k = 0; k < 3; ++k) {
        const int gsrc = (j + k + 3) & 3;
        hv4 kd9[9];
#pragma unroll
        for (int t9 = 0; t9 < 9; ++t9) {
            int dy = t9 / 3, dx = t9 % 3;
            int i, jj;
            ROT_G(j, dy, dx, i, jj);
            kd9[t9] = f4_to_hv4(ker4[((i * 3 + jj) * 3 + k) * 32 + c * 4 + q]);
        }
        // taps at wp = w, w+1, w+2 -> hv4 offsets +0, +32, +64
        const size_t pb = ((size_t)(b * 4 + gsrc) * HH * 66 + w) * 32 + c * 4 + q;
#pragma unroll
        for (int ei = 0; ei < 10; ++ei) {
            const int er = hs * 8 - 1 + ei;
            if ((unsigned)er >= HH) continue;           // wave-uniform
            const size_t rb = pb + (size_t)er * 66 * 32;
            hv4 e0 = ero[rb];
            hv4 e1 = ero[rb + 32];
            hv4 e2 = ero[rb + 64];
#pragma unroll
            for (int dy = 0; dy < 3; ++dy) {
                const int rr = ei - dy;                  // out local row
                if ((unsigned)rr >= 8) continue;
                acc[rr] = __builtin_elementwise_max(acc[rr], e0 + kd9[dy * 3 + 0]);
                acc[rr] = __builtin_elementwise_max(acc[rr], e1 + kd9[dy * 3 + 1]);
                acc[rr] = __builtin_elementwise_max(acc[rr], e2 + kd9[dy * 3 + 2]);
            }
        }
    }

    // c-sum in f32 via xor-shuffle (c = lane bits 2..4), then store
    float4* out4 = (float4*)out;
    const int bjbase = (b * 4 + j) * HH + hs * 8;
#pragma unroll
    for (int r = 0; r < 8; ++r) {
        float4 s = make_float4((float)acc[r].x, (float)acc[r].y,
                               (float)acc[r].z, (float)acc[r].w);
#pragma unroll
        for (int off = 4; off <= 16; off <<= 1) {
            s.x += __shfl_xor(s.x, off, 64);
            s.y += __shfl_xor(s.y, off, 64);
            s.z += __shfl_xor(s.z, off, 64);
            s.w += __shfl_xor(s.w, off, 64);
        }
        if (c == 0)
            out4[((size_t)(bjbase + r) * WW + w) * 4 + q] = s;
    }
}

// ============== fallback: PASSED fused kernel (258 us, R5) ==============
__global__ __launch_bounds__(256, 3) void opening_fused_fb(
    const float* __restrict__ x, const float* __restrict__ ker, float* __restrict__ out)
{
    __shared__ __align__(16) float xs[8 * 4 * 144];
    __shared__ float4 es4[4 * 4 * 100];
    __shared__ float4 ke4[27 * 4 * 4];
    __shared__ float4 kd4[9 * 4 * 4];

    const int tid = threadIdx.x;
    const int tileX = blockIdx.x & 7;
    const int tileY = (blockIdx.x >> 3) & 7;
    const int j = (blockIdx.x >> 6) & 3;
    const int b = blockIdx.x >> 8;
    const float4* ker4 = (const float4*)ker;
    const float4* x4 = (const float4*)x;

    for (int t = tid; t < 1152; t += 256) {
        int q01 = t & 1;
        int cell = t >> 1;
        int g = cell / 144;
        int rem = cell - g * 144;
        int r = rem / 12;
        int s = rem - r * 12;
        int h = tileY * 8 - 2 + r;
        int w = tileX * 8 - 2 + s;
        float4 v;
        if ((unsigned)h < HH && (unsigned)w < WW)
            v = x4[(((b * 4 + g) * HH + h) * WW + w) * 2 + q01];
        else
            v = make_float4(POS_INF, POS_INF, POS_INF, POS_INF);
        int c0 = q01 * 4;
        xs[((c0 + 0) * 4 + g) * 144 + rem] = v.x;
        xs[((c0 + 1) * 4 + g) * 144 + rem] = v.y;
        xs[((c0 + 2) * 4 + g) * 144 + rem] = v.z;
        xs[((c0 + 3) * 4 + g) * 144 + rem] = v.w;
    }
    __syncthreads();

    const int q_o = tid & 3;
    const int ox = (tid >> 2) & 7;
    const int oy = tid >> 5;

    float4 acc[8];
#pragma unroll
    for (int c = 0; c < 8; ++c)
        acc[c] = make_float4(NEG_INF, NEG_INF, NEG_INF, NEG_INF);

    for (int k = 0; k < 3; ++k) {
        const int gsrc = (j + k + 3) & 3;
#pragma unroll
        for (int cg = 0; cg < 2; ++cg) {
            for (int t = tid; t < 576; t += 256) {
                if (t < 432) {
                    int q = t & 3;
                    int c4 = (t >> 2) & 3;
                    int tap = t >> 4;
                    int k2 = tap % 3;
                    int dxdy = tap / 3;
                    int dx = dxdy % 3;
                    int dy = dxdy / 3;
                    int a0 = 2 - dy, b0 = 2 - dx;
                    int i, jj;
                    ROT_G(gsrc, a0, b0, i, jj);
                    int ka, kb, kc;
                    if (k2 == 0)      { ka = 2 - jj; kb = i;      kc = 2; }
                    else if (k2 == 1) { ka = i;      kb = jj;     kc = 1; }
                    else              { ka = jj;     kb = 2 - i;  kc = 0; }
                    int c = cg * 4 + c4;
                    ke4[t] = ker4[((ka * 3 + kb) * 3 + kc) * 32 + c * 4 + q];
                } else {
                    int u = t - 432;
                    int q = u & 3;
                    int c4 = (u >> 2) & 3;
                    int dydx = u >> 4;
                    int dx = dydx % 3;
                    int dy = dydx / 3;
                    int i, jj;
                    ROT_G(j, dy, dx, i, jj);
                    int c = cg * 4 + c4;
                    kd4[u] = ker4[((i * 3 + jj) * 3 + k) * 32 + c * 4 + q];
                }
            }
            __syncthreads();

            for (int it = 0; it < 2; ++it) {
                int id = tid + (it << 8);
                int c4 = id >> 7;
                int p = id & 127;
                if (p >= 100) continue;
                int ey = (p * 205) >> 11;
                int ex = p - ey * 10;
                int h_es = tileY * 8 - 1 + ey;
                int w_es = tileX * 8 - 1 + ex;
                float4 b0, b1, b2, b3;
                if ((unsigned)h_es < HH && (unsigned)w_es < WW) {
                    b0 = b1 = b2 = b3 = make_float4(POS_INF, POS_INF, POS_INF, POS_INF);
                    int c = cg * 4 + c4;
#pragma unroll
                    for (int k2 = 0; k2 < 3; ++k2) {
                        int g2 = (gsrc + k2 + 3) & 3;
                        int base = (c * 4 + g2) * 144 + ey * 12 + ex;
#pragma unroll
                        for (int dy = 0; dy < 3; ++dy)
#pragma unroll
                            for (int dx = 0; dx < 3; ++dx) {
                                float v = xs[base + dy * 12 + dx];
                                const float4* kk = &ke4[(((dy * 3 + dx) * 3 + k2) * 4 + c4) * 4];
                                float4 kv;
                                kv = kk[0];
                                b0.x = fminf(b0.x, v - kv.x); b0.y = fminf(b0.y, v - kv.y);
                                b0.z = fminf(b0.z, v - kv.z); b0.w = fminf(b0.w, v - kv.w);
                                kv = kk[1];
                                b1.x = fminf(b1.x, v - kv.x); b1.y = fminf(b1.y, v - kv.y);
                                b1.z = fminf(b1.z, v - kv.z); b1.w = fminf(b1.w, v - kv.w);
                                kv = kk[2];
                                b2.x = fminf(b2.x, v - kv.x); b2.y = fminf(b2.y, v - kv.y);
                                b2.z = fminf(b2.z, v - kv.z); b2.w = fminf(b2.w, v - kv.w);
                                kv = kk[3];
                                b3.x = fminf(b3.x, v - kv.x); b3.y = fminf(b3.y, v - kv.y);
                                b3.z = fminf(b3.z, v - kv.z); b3.w = fminf(b3.w, v - kv.w);
                            }
                    }
                } else {
                    b0 = b1 = b2 = b3 = make_float4(NEG_INF, NEG_INF, NEG_INF, NEG_INF);
                }
                int eb = (c4 * 4) * 100 + p;
                es4[eb] = b0; es4[eb + 100] = b1; es4[eb + 200] = b2; es4[eb + 300] = b3;
            }
            __syncthreads();

#pragma unroll
            for (int c4 = 0; c4 < 4; ++c4) {
                float4 a = acc[cg * 4 + c4];
#pragma unroll
                for (int dy = 0; dy < 3; ++dy)
#pragma unroll
                    for (int dx = 0; dx < 3; ++dx) {
                        int pos = (oy + dy) * 10 + (ox + dx);
                        float4 e = es4[(c4 * 4 + q_o) * 100 + pos];
                        float4 kv = kd4[(dy * 3 + dx) * 16 + c4 * 4 + q_o];
                        a.x = fmaxf(a.x, e.x + kv.x);
                        a.y = fmaxf(a.y, e.y + kv.y);
                        a.z = fmaxf(a.z, e.z + kv.z);
                        a.w = fmaxf(a.w, e.w + kv.w);
                    }
                acc[cg * 4 + c4] = a;
            }
            __syncthreads();
        }
    }

    float4 s = acc[0];
#pragma unroll
    for (int c = 1; c < 8; ++c) {
        s.x += acc[c].x; s.y += acc[c].y; s.z += acc[c].z; s.w += acc[c].w;
    }
    const int h = tileY * 8 + oy;
    const int w = tileX * 8 + ox;
    ((float4*)out)[(((b * 4 + j) * HH + h) * WW + w) * 4 + q_o] = s;
}

extern "C" void kernel_launch(void* const* d_in, const int* in_sizes, int n_in,
                              void* d_out, int out_size, void* d_ws, size_t ws_size,
                              hipStream_t stream) {
    const float* x = (const float*)d_in[0];
    const float* ker = (const float*)d_in[1];
    float* out = (float*)d_out;

    const size_t ero_f16_bytes = (size_t)16 * HH * 66 * 32 * 8;   // 17,301,504

    if (ws_size >= ero_f16_bytes) {
        hv4* ero = (hv4*)d_ws;
        erode_t<<<1024, 256, 0, stream>>>(x, ker, ero);
        dilate_t<<<1024, 256, 0, stream>>>(ero, ker, out);
    } else {
        opening_fused_fb<<<1024, 256, 0, stream>>>(x, ker, out);
    }
}